// Round 3
// baseline (1190.308 us; speedup 1.0000x reference)
//
#include <hip/hip_runtime.h>
#include <math.h>

// ---------------------------------------------------------------------------
// SpectralConv2d: sigma = tensor-spectral-norm(w) via 20 complex power its,
// then y = conv2d_same(x, w/sigma, NHWC, 3x3) + bias.
// B=32 H=W=64 CIN=COUT=256 KH=KW=3.
// Round 6: T-factorization of the power iteration — ONE device barrier per
// iteration (22 phases total, was 41):
//   T_i[hw] = sum_o conj(a_o) K[o,i,hw]  (the only cross-block reduction)
//   M[hw]   = sum_i conj(b_i) T_i[hw]            (intra-block)
//   pb_i    = sum_hw T_i[hw] qv[hw]              (thread-local!)
//   a_o     = sum_i conj(b_new) g_{o,i}          (intra-block)
// 16 blocks x 512 threads; thread (os,i) owns 8 couts (kr[8][9] VGPRs,
// launch_bounds(512,2) -> 256-VGPR cap). T partials in the wt3 region
// (guard barrier before final wt3 writes). conv / xprep unchanged (proven).
// ---------------------------------------------------------------------------

#define EPSN 1e-12f

// ---- workspace layout (bytes) ----
// xb  : bf16 padded input  [32][66][66][256]          = 71,368,704 B
// wt3 : bf16 weights       [9tap][256cout][256ci]     =  1,179,648 B
//       (first 327,680 B double as Tpart[16][256][20] floats during iters)
// ctrl: float control area                            =    135,168 B
#define XB_OFF   0
#define WT_OFF   71368704
#define CTRL_OFF 72548352

// ctrl offsets (floats); cross-block data via AGENT-scope atomics only.
#define CTRL_FLAG 0      // int flags[16]  epoch barrier (monotone per launch)
#define CTRL_NA   64     // float naP[16]  per-block sum |a|^2 partials

#define NPB 16           // power-kernel blocks

struct c2 { float x, y; };
__device__ inline c2 cadd(c2 a, c2 b) { return {a.x + b.x, a.y + b.y}; }
__device__ inline c2 cmul(c2 a, c2 b) { return {a.x * b.x - a.y * b.y, a.x * b.y + a.y * b.x}; }
__device__ inline c2 cjg(c2 a) { return {a.x, -a.y}; }
__device__ inline c2 cscale(c2 a, float s) { return {a.x * s, a.y * s}; }

__device__ inline unsigned short f2bf(float f) {  // RNE fp32->bf16
    unsigned int u = __float_as_uint(f);
    unsigned int r = u + 0x7fffu + ((u >> 16) & 1u);
    return (unsigned short)(r >> 16);
}

typedef __bf16 bf16x8 __attribute__((ext_vector_type(8)));
typedef float  f32x4  __attribute__((ext_vector_type(4)));

__device__ __forceinline__ void gl_lds16(const unsigned short* g, unsigned short* l) {
    __builtin_amdgcn_global_load_lds(
        (const __attribute__((address_space(1))) unsigned int*)g,
        (__attribute__((address_space(3))) unsigned int*)l, 16, 0, 0);
}

// agent-scope helpers (coherent at LLC; per-XCD L2s never hold this data)
__device__ __forceinline__ float ald(const float* p) {
    return __hip_atomic_load(p, __ATOMIC_RELAXED, __HIP_MEMORY_SCOPE_AGENT);
}
__device__ __forceinline__ void ast32(float* p, float v) {
    __hip_atomic_store(p, v, __ATOMIC_RELAXED, __HIP_MEMORY_SCOPE_AGENT);
}
__device__ __forceinline__ void ast64(unsigned long long* p, c2 v) {
    union { c2 c; unsigned long long u; } cv; cv.c = v;
    __hip_atomic_store(p, cv.u, __ATOMIC_RELAXED, __HIP_MEMORY_SCOPE_AGENT);
}
__device__ __forceinline__ c2 ald64(const unsigned long long* p) {
    union { c2 c; unsigned long long u; } cv;
    cv.u = __hip_atomic_load(p, __ATOMIC_RELAXED, __HIP_MEMORY_SCOPE_AGENT);
    return cv.c;
}

// Flag-epoch device barrier over NPB co-resident blocks (cooperative launch).
// Entry __syncthreads drains each wave's vmcnt, so all agent-scope stores are
// at LLC before the arrival is published. One RELEASE store per block; lanes
// 0..15 of wave 0 poll the 16 peer flags. Epochs monotone per launch.
__device__ __forceinline__ void gbar(int* flags, int bid, int tid, int epoch) {
    __syncthreads();
    if (tid == 0)
        __hip_atomic_store(&flags[bid], epoch, __ATOMIC_RELEASE, __HIP_MEMORY_SCOPE_AGENT);
    if (tid < NPB) {
        while (__hip_atomic_load(&flags[tid], __ATOMIC_RELAXED, __HIP_MEMORY_SCOPE_AGENT) < epoch)
            __builtin_amdgcn_s_sleep(1);
    }
    __syncthreads();
}

// ---------------------------------------------------------------------------
// xprep: x fp32 NHWC -> padded bf16 [32][66][66][256]; block 0 zeroes ctrl.
// grid: 34848 x 256
// ---------------------------------------------------------------------------
__global__ __launch_bounds__(256) void k_xprep(const float* __restrict__ x,
                                               unsigned short* __restrict__ xb,
                                               float* __restrict__ ctrl) {
    int flat = blockIdx.x * 256 + threadIdx.x;
    int c4   = flat & 63;
    int rest = flat >> 6;                           // (b*66+hh)*66+ww
    int ww   = rest % 66;
    int r2   = rest / 66;
    int hh   = r2 % 66;
    int b    = r2 / 66;
    int h = hh - 1, w2 = ww - 1;
    ushort4 outv;
    if (h >= 0 && h < 64 && w2 >= 0 && w2 < 64) {
        const float4 v = *(const float4*)(x + ((((b << 6) + h) << 6) + w2) * 256 + (c4 << 2));
        outv.x = f2bf(v.x); outv.y = f2bf(v.y); outv.z = f2bf(v.z); outv.w = f2bf(v.w);
    } else {
        outv.x = 0; outv.y = 0; outv.z = 0; outv.w = 0;
    }
    *(ushort4*)(xb + ((size_t)rest << 8) + (c4 << 2)) = outv;
    if (blockIdx.x == 0 && threadIdx.x < 256) {     // zero flags/naP (first 512 floats)
        ctrl[threadIdx.x]       = 0.f;
        ctrl[threadIdx.x + 256] = 0.f;
    }
}

// ---------------------------------------------------------------------------
// k_power: 20-iteration power method + sigma + weight transform, fused.
// Cooperative launch: 16 blocks x 512. thread=(os=tid>>8, i=tid&255);
// block owns couts [bid*16, bid*16+16), thread owns 8 of them
// (o = bid*16 + os*8 + p). kr[8][9] in VGPRs. Per iteration exactly one
// cross-block phase: the T reduction (partials in wt3 region, own-slot
// ast64 stores, fully parallel ald64 gather). Everything else intra-block.
// ---------------------------------------------------------------------------
__global__ __launch_bounds__(512, 2) void k_power(const float* __restrict__ w,
                                                  const float* __restrict__ u1,
                                                  const float* __restrict__ u2,
                                                  const float* __restrict__ u3,
                                                  float* __restrict__ ctrl,
                                                  unsigned short* __restrict__ wt3) {
    const int tid  = threadIdx.x, bid = blockIdx.x;
    const int os   = tid >> 8, i = tid & 255;
    const int lane = tid & 63, wid = tid >> 6;

    int*   flags = (int*)(ctrl + CTRL_FLAG);
    float* naP   = ctrl + CTRL_NA;
    float* Tpart = (float*)wt3;          // [16][256][20] floats = 327,680 B

    __shared__ float shA[256][21];       // gather half A (os=0) / scratch
    __shared__ float shB[256][21];       // T-partial combine + gather half B
    __shared__ float redw[8][21];        // per-wave reduction partials
    __shared__ float msm[18];            // M broadcast
    __shared__ float af[32];             // a broadcast: [16 couts][2]
    __shared__ float nbshare, nash;

    // per-thread: 8 couts x 9 taps of K, and their a values
    float kr[8][9];
    c2    a[8];
    #pragma unroll
    for (int p = 0; p < 8; ++p) {
        const int o = (bid << 4) + (os << 3) + p;
        const float* wr = w + (size_t)((o << 8) + i) * 9;
        #pragma unroll
        for (int j = 0; j < 9; ++j) kr[p][j] = wr[j];
        a[p] = ((const c2*)u1)[o];
    }
    c2 b = ((const c2*)u2)[i];
    c2 cpr[3];
    #pragma unroll
    for (int h = 0; h < 3; ++h) cpr[h] = ((const c2*)u3)[h];

    for (int t = 0; t <= 20; ++t) {
        // ---- T-partial over own 8 couts: Tp_i[hw] = sum_p kr[p][hw] conj(a_p)
        float Tp[18];
        #pragma unroll
        for (int hw = 0; hw < 9; ++hw) {
            float sx = 0.f, sy = 0.f;
            #pragma unroll
            for (int p = 0; p < 8; ++p) { sx += kr[p][hw] * a[p].x; sy -= kr[p][hw] * a[p].y; }
            Tp[2 * hw] = sx; Tp[2 * hw + 1] = sy;
        }
        // combine os halves (deterministic order: os0 + os1), os=0 stores slot
        if (os == 1) {
            #pragma unroll
            for (int j = 0; j < 18; ++j) shB[i][j] = Tp[j];
        }
        __syncthreads();
        if (os == 0) {
            #pragma unroll
            for (int j = 0; j < 18; ++j) Tp[j] += shB[i][j];
            unsigned long long* dst = (unsigned long long*)(Tpart + ((bid << 8) + i) * 20);
            #pragma unroll
            for (int j2 = 0; j2 < 9; ++j2) ast64(dst + j2, c2{Tp[2 * j2], Tp[2 * j2 + 1]});
        }
        if (t == 20 && tid == 0) {       // ||a(20)||^2 partial (af = a(20))
            float s = 0.f;
            #pragma unroll
            for (int k = 0; k < 32; ++k) s += af[k] * af[k];
            ast32(naP + bid, s);
        }
        gbar(flags, bid, tid, t + 1);

        // ---- gather T: thread (os,i) sums partials k = os*8..os*8+7, row i
        {
            float gs[18];
            #pragma unroll
            for (int j = 0; j < 18; ++j) gs[j] = 0.f;
            #pragma unroll
            for (int k = 0; k < 8; ++k) {
                const unsigned long long* src =
                    (const unsigned long long*)(Tpart + ((((os << 3) + k) << 8) + i) * 20);
                c2 v[9];
                #pragma unroll
                for (int j2 = 0; j2 < 9; ++j2) v[j2] = ald64(src + j2);
                #pragma unroll
                for (int j2 = 0; j2 < 9; ++j2) { gs[2 * j2] += v[j2].x; gs[2 * j2 + 1] += v[j2].y; }
            }
            if (os == 0) {
                #pragma unroll
                for (int j = 0; j < 18; ++j) shA[i][j] = gs[j];
            } else {
                #pragma unroll
                for (int j = 0; j < 18; ++j) shB[i][j] = gs[j];
            }
        }
        __syncthreads();
        float T[18];
        #pragma unroll
        for (int j = 0; j < 18; ++j) T[j] = shA[i][j] + shB[i][j];

        // ---- M[hw] = 0.5 * sum_{512 threads} conj(b) * T_i[hw]  (each i twice)
        {
            float mv[18];
            #pragma unroll
            for (int hw = 0; hw < 9; ++hw) {
                c2 m = cmul(cjg(b), c2{T[2 * hw], T[2 * hw + 1]});
                mv[2 * hw] = m.x; mv[2 * hw + 1] = m.y;
            }
            #pragma unroll
            for (int j = 0; j < 18; ++j)
                #pragma unroll
                for (int off = 32; off; off >>= 1) mv[j] += __shfl_down(mv[j], off);
            if (lane == 0) {
                #pragma unroll
                for (int j = 0; j < 18; ++j) redw[wid][j] = mv[j];
            }
            __syncthreads();
            if (tid < 18) {
                float s = 0.f;
                #pragma unroll
                for (int k = 0; k < 8; ++k) s += redw[k][tid];
                msm[tid] = 0.5f * s;
            }
            __syncthreads();
        }
        if (t == 20) break;

        // ---- d, c, qv from M (replicated tiny compute) ----
        float m[18];
        #pragma unroll
        for (int j = 0; j < 18; ++j) m[j] = msm[j];

        c2 dv[3]; float nd2 = 0.f;
        #pragma unroll
        for (int w2 = 0; w2 < 3; ++w2) {
            c2 s = {0.f, 0.f};
            #pragma unroll
            for (int h = 0; h < 3; ++h) {
                c2 mc = {m[2 * (h * 3 + w2)], m[2 * (h * 3 + w2) + 1]};
                s = cadd(s, cmul(mc, cjg(cpr[h])));
            }
            dv[w2] = s; nd2 += s.x * s.x + s.y * s.y;
        }
        {
            float inv = 1.f / (sqrtf(nd2) + EPSN);
            #pragma unroll
            for (int w2 = 0; w2 < 3; ++w2) dv[w2] = cscale(dv[w2], inv);
        }
        c2 cn[3]; float nc2 = 0.f;
        #pragma unroll
        for (int h = 0; h < 3; ++h) {
            c2 s = {0.f, 0.f};
            #pragma unroll
            for (int w2 = 0; w2 < 3; ++w2) {
                c2 mc = {m[2 * (h * 3 + w2)], m[2 * (h * 3 + w2) + 1]};
                s = cadd(s, cmul(mc, cjg(dv[w2])));
            }
            cn[h] = s; nc2 += s.x * s.x + s.y * s.y;
        }
        {
            float inv = 1.f / (sqrtf(nc2) + EPSN);
            #pragma unroll
            for (int h = 0; h < 3; ++h) cn[h] = cscale(cn[h], inv);
        }
        c2 qv[9];
        #pragma unroll
        for (int h = 0; h < 3; ++h)
            #pragma unroll
            for (int w2 = 0; w2 < 3; ++w2)
                qv[h * 3 + w2] = cjg(cmul(cn[h], dv[w2]));

        // ---- pb_i = sum_hw T_i[hw] * qv[hw]  (thread-local!) ----
        c2 pb = {0.f, 0.f};
        #pragma unroll
        for (int hw = 0; hw < 9; ++hw)
            pb = cadd(pb, cmul(c2{T[2 * hw], T[2 * hw + 1]}, qv[hw]));

        // b-norm: n2 = 0.5 * sum_{512} |pb_i|^2 (each i twice)
        {
            float n2 = pb.x * pb.x + pb.y * pb.y;
            #pragma unroll
            for (int off = 32; off; off >>= 1) n2 += __shfl_down(n2, off);
            if (lane == 0) redw[wid][0] = n2;
            __syncthreads();
            if (tid == 0) {
                float acc = 0.f;
                #pragma unroll
                for (int k = 0; k < 8; ++k) acc += redw[k][0];
                nbshare = sqrtf(acc * 0.5f);
            }
            __syncthreads();
        }
        b = cscale(pb, 1.f / (nbshare + EPSN));

        // ---- a_p = sum_i conj(b_new) g_{p,i}; per-os-group reduction ----
        {
            float vv[16];
            #pragma unroll
            for (int p = 0; p < 8; ++p) {
                float gx = 0.f, gy = 0.f;
                #pragma unroll
                for (int j = 0; j < 9; ++j) { gx += kr[p][j] * qv[j].x; gy += kr[p][j] * qv[j].y; }
                c2 ctr = cmul(cjg(b), c2{gx, gy});
                vv[2 * p] = ctr.x; vv[2 * p + 1] = ctr.y;
            }
            #pragma unroll
            for (int j = 0; j < 16; ++j)
                #pragma unroll
                for (int off = 32; off; off >>= 1) vv[j] += __shfl_down(vv[j], off);
            if (lane == 0) {
                #pragma unroll
                for (int j = 0; j < 16; ++j) redw[wid][j] = vv[j];
            }
            __syncthreads();
            if (tid < 32) {                 // og = waves 0-3 (os0) / 4-7 (os1)
                int og = tid >> 4, j = tid & 15;
                float s = 0.f;
                #pragma unroll
                for (int k = 0; k < 4; ++k) s += redw[(og << 2) + k][j];
                af[(og << 4) + j] = s;      // cout (og*8 + j/2), comp j&1
            }
            __syncthreads();
        }
        #pragma unroll
        for (int p = 0; p < 8; ++p) a[p] = c2{af[(os << 4) + 2 * p], af[(os << 4) + 2 * p + 1]};
        #pragma unroll
        for (int h = 0; h < 3; ++h) cpr[h] = cn[h];
    }

    // ---- tail: sigma from M(20), cpr=c(20); wt3 = bf16(w/sigma) ----
    float m[18];
    #pragma unroll
    for (int j = 0; j < 18; ++j) m[j] = msm[j];
    c2 dv[3]; float nd2 = 0.f;
    #pragma unroll
    for (int w2 = 0; w2 < 3; ++w2) {
        c2 s = {0.f, 0.f};
        #pragma unroll
        for (int h = 0; h < 3; ++h) {
            c2 mc = {m[2 * (h * 3 + w2)], m[2 * (h * 3 + w2) + 1]};
            s = cadd(s, cmul(mc, cjg(cpr[h])));
        }
        dv[w2] = s; nd2 += s.x * s.x + s.y * s.y;
    }
    {
        float inv = 1.f / (sqrtf(nd2) + EPSN);
        #pragma unroll
        for (int w2 = 0; w2 < 3; ++w2) dv[w2] = cscale(dv[w2], inv);
    }
    c2 sg = {0.f, 0.f};
    #pragma unroll
    for (int h = 0; h < 3; ++h)
        #pragma unroll
        for (int w2 = 0; w2 < 3; ++w2) {
            c2 mc = {m[2 * (h * 3 + w2)], m[2 * (h * 3 + w2) + 1]};
            sg = cadd(sg, cmul(mc, cjg(cmul(cpr[h], dv[w2]))));
        }
    if (tid == 0) {
        float s = 0.f;
        #pragma unroll
        for (int k = 0; k < NPB; ++k) s += ald(naP + k);
        nash = s;
    }
    __syncthreads();
    float na     = sqrtf(nash);
    float invsig = (na + EPSN) / (sqrtf(sg.x * sg.x + sg.y * sg.y) + EPSN);

    // guard: all blocks' Tpart reads (aliasing wt3) done before wt3 writes
    gbar(flags, bid, tid, 22);

    #pragma unroll
    for (int p = 0; p < 8; ++p) {
        const int o = (bid << 4) + (os << 3) + p;
        #pragma unroll
        for (int tap = 0; tap < 9; ++tap)
            wt3[(size_t)tap * 65536 + (o << 8) + i] = f2bf(kr[p][tap] * invsig);
    }
}

// ---------------------------------------------------------------------------
// conv v3: LDS-staged implicit GEMM, BK=64 (m97 config).
// Block = 128 pixels (2 rows x 64 cols) x 128 couts, 256 threads, 4 waves
// (2x2 of 64x64). 36 staging rounds (9 taps x 4 cc64); per round stage
// A 16KB + B 16KB via global_load_lds(16B), then 32 MFMA/wave.
// LDS layout [ks][128][32] keeps the measured conflict-free pattern.
// grid: 2048.  bid = (pixel_block<<1)|nb ; pixel_block = (b<<5)|hp
// ---------------------------------------------------------------------------
__global__ __launch_bounds__(256) void k_conv(const unsigned short* __restrict__ xb,
                                              const unsigned short* __restrict__ wt3,
                                              const float* __restrict__ bias,
                                              float* __restrict__ y) {
    __shared__ unsigned short lA[8192];   // [2 ks][128 pix][32 ch]
    __shared__ unsigned short lB[8192];   // [2 ks][128 cout][32 ci]
    const int tid  = threadIdx.x, bid = blockIdx.x;
    const int lane = tid & 63, wid = tid >> 6;
    const int l15  = lane & 15, q = lane >> 4;
    const int pbk  = bid >> 1, nb = bid & 1;
    const int b    = pbk >> 5, hp = pbk & 31, h0 = hp << 1;
    const int mh   = (wid & 1) << 6;
    const int nq   = (wid >> 1) << 6;
    const int n_off = (nb << 7) + nq;

    // staging unit u = j*256+tid (j=0..3): elem = (u>>9)*32 + (u&3)*8 within
    // the 64-ch K-block; pix/cout = (u>>2)&127 ; LDS off = u*8 ushorts.
    int ag[4], bg[4];
    #pragma unroll
    for (int j = 0; j < 4; ++j) {
        int u   = (j << 8) + tid;
        int pix = (u >> 2) & 127;
        int ce  = ((u >> 9) << 5) + ((u & 3) << 3);
        int r   = pix >> 6, c = pix & 63;
        ag[j] = ((b * 66 + h0 + r) * 66 + c) * 256 + ce;
        bg[j] = (nb << 15) + (pix << 8) + ce;          // pix plays cout_local
    }
    unsigned short* lAd = lA + (tid << 3);
    unsigned short* lBd = lB + (tid << 3);

    f32x4 acc[4][4];
    #pragma unroll
    for (int ms = 0; ms < 4; ++ms)
        #pragma unroll
        for (int ns = 0; ns < 4; ++ns) acc[ms][ns] = {0.f, 0.f, 0.f, 0.f};

    #pragma unroll 1
    for (int tap = 0; tap < 9; ++tap) {
        const int kh = tap / 3, kw = tap % 3;
        const int aoff = (kh * 66 + kw) * 256;
        const int boff = tap << 16;
        #pragma unroll 1
        for (int cc = 0; cc < 4; ++cc) {
            const int cco = cc << 6;
            __syncthreads();
            #pragma unroll
            for (int j = 0; j < 4; ++j) {
                gl_lds16(xb  + ag[j] + aoff + cco, lAd + (j << 11));
                gl_lds16(wt3 + bg[j] + boff + cco, lBd + (j << 11));
            }
            __syncthreads();
            #pragma unroll
            for (int ks = 0; ks < 2; ++ks) {
                bf16x8 av[4], bv[4];
                #pragma unroll
                for (int ms = 0; ms < 4; ++ms)
                    av[ms] = *(const bf16x8*)(lA + (ks << 12) + ((mh + (ms << 4) + l15) << 5) + (q << 3));
                #pragma unroll
                for (int ns = 0; ns < 4; ++ns)
                    bv[ns] = *(const bf16x8*)(lB + (ks << 12) + ((nq + (ns << 4) + l15) << 5) + (q << 3));
                #pragma unroll
                for (int ms = 0; ms < 4; ++ms)
                    #pragma unroll
                    for (int ns = 0; ns < 4; ++ns)
                        acc[ms][ns] = __builtin_amdgcn_mfma_f32_16x16x32_bf16(
                            av[ms], bv[ns], acc[ms][ns], 0, 0, 0);
            }
        }
    }

    float bias_v[4];
    #pragma unroll
    for (int ns = 0; ns < 4; ++ns) bias_v[ns] = bias[n_off + (ns << 4) + l15];

    #pragma unroll
    for (int ms = 0; ms < 4; ++ms) {
        const int pb2 = mh + (ms << 4) + (q << 2);
        #pragma unroll
        for (int r2 = 0; r2 < 4; ++r2) {
            const int pr = pb2 + r2;
            const int h = h0 + (pr >> 6), wc = pr & 63;
            float* yr = y + ((((b << 6) + h) << 6) + wc) * 256 + n_off;
            #pragma unroll
            for (int ns = 0; ns < 4; ++ns)
                yr[(ns << 4) + l15] = acc[ms][ns][r2] + bias_v[ns];
        }
    }
}

// ---------------------------------------------------------------------------
extern "C" void kernel_launch(void* const* d_in, const int* in_sizes, int n_in,
                              void* d_out, int out_size, void* d_ws, size_t ws_size,
                              hipStream_t stream) {
    const float* x    = (const float*)d_in[0];
    const float* w    = (const float*)d_in[1];
    const float* bias = (const float*)d_in[2];
    const float* u1   = (const float*)d_in[3];   // complex64 interleaved
    const float* u2   = (const float*)d_in[4];
    const float* u3   = (const float*)d_in[5];
    float* y = (float*)d_out;

    char* ws = (char*)d_ws;
    unsigned short* xb = (unsigned short*)(ws + XB_OFF);
    unsigned short* wt = (unsigned short*)(ws + WT_OFF);
    float*          ct = (float*)(ws + CTRL_OFF);

    k_xprep<<<34848, 256, 0, stream>>>(x, xb, ct);

    void* args[] = {(void*)&w, (void*)&u1, (void*)&u2, (void*)&u3, (void*)&ct, (void*)&wt};
    hipLaunchCooperativeKernel((const void*)k_power, dim3(NPB), dim3(512), args, 0, stream);

    k_conv<<<2048, 256, 0, stream>>>(xb, wt, bias, y);
}

// Round 5
// 1080.798 us; speedup vs baseline: 1.1013x; 1.1013x over previous
//
#include <hip/hip_runtime.h>
#include <math.h>

// ---------------------------------------------------------------------------
// SpectralConv2d: sigma = tensor-spectral-norm(w) via 20 complex power its,
// then y = conv2d_same(x, w/sigma, NHWC, 3x3) + bias.
// B=32 H=W=64 CIN=COUT=256 KH=KW=3.
// Round 8: RESUBMIT of round 7 (bench infra failed twice; source audited —
// no hang paths: k_conv has no barriers/spins, k_power is the r3-proven
// cooperative kernel).
//   - k_power: r3-verbatim (330us, VGPR 56).
//   - k_conv v4: ZERO-LDS register implicit GEMM; per-lane 16B global
//     gathers feed MFMA fragments directly (same bytes the LDS path
//     produced). B (wt3, 1.18MB) L2-resident; A (xb) 18x L2/LLC reuse.
//     No __syncthreads, no gl_lds drain -> loads pipeline across rounds.
// ---------------------------------------------------------------------------

#define EPSN 1e-12f

// ---- workspace layout (bytes) ----
// xb  : bf16 padded input  [32][66][66][256]          = 71,368,704 B
// wt3 : bf16 weights       [9tap][256cout][256ci]     =  1,179,648 B
// ctrl: float control area (33792 floats)             =    135,168 B
#define XB_OFF   0
#define WT_OFF   71368704
#define CTRL_OFF 72548352

// ctrl offsets (floats). All cross-block data accessed via AGENT-scope
// atomics only (coherent at LLC; per-XCD L2s never hold it).
#define CTRL_BAR 0      // int bar[64]   barrier arrival slots (one per sync)
#define CTRL_M   64     // M[21][18]     unique slot per iteration
#define CTRL_NA  448    // sum |a|^2
#define CTRL_PB  1024   // pb[64][256] complex (overwrite-only, no zeroing)

#define NPB 64          // power-kernel blocks

struct c2 { float x, y; };
__device__ inline c2 cadd(c2 a, c2 b) { return {a.x + b.x, a.y + b.y}; }
__device__ inline c2 cmul(c2 a, c2 b) { return {a.x * b.x - a.y * b.y, a.x * b.y + a.y * b.x}; }
__device__ inline c2 cjg(c2 a) { return {a.x, -a.y}; }
__device__ inline c2 cscale(c2 a, float s) { return {a.x * s, a.y * s}; }

__device__ inline unsigned short f2bf(float f) {  // RNE fp32->bf16
    unsigned int u = __float_as_uint(f);
    unsigned int r = u + 0x7fffu + ((u >> 16) & 1u);
    return (unsigned short)(r >> 16);
}

typedef __bf16 bf16x8 __attribute__((ext_vector_type(8)));
typedef float  f32x4  __attribute__((ext_vector_type(4)));

// agent-scope helpers (bypass non-coherent L2, live at LLC)
__device__ __forceinline__ float ald(const float* p) {
    return __hip_atomic_load(p, __ATOMIC_RELAXED, __HIP_MEMORY_SCOPE_AGENT);
}
__device__ __forceinline__ void aadd(float* p, float v) {
    __hip_atomic_fetch_add(p, v, __ATOMIC_RELAXED, __HIP_MEMORY_SCOPE_AGENT);
}
__device__ __forceinline__ void ast64(unsigned long long* p, c2 v) {
    union { c2 c; unsigned long long u; } cv; cv.c = v;
    __hip_atomic_store(p, cv.u, __ATOMIC_RELAXED, __HIP_MEMORY_SCOPE_AGENT);
}
__device__ __forceinline__ c2 ald64(const unsigned long long* p) {
    union { c2 c; unsigned long long u; } cv;
    cv.u = __hip_atomic_load(p, __ATOMIC_RELAXED, __HIP_MEMORY_SCOPE_AGENT);
    return cv.c;
}

// Device barrier over NPB blocks. Requires co-residency (cooperative launch).
// Writers' vmcnt drained by the entry __syncthreads; RELEASE on the arrival
// add orders it; readers use agent-scope loads so no invalidate needed.
__device__ __forceinline__ void gbar(int* bar, int slot, int tid) {
    __syncthreads();
    if (tid == 0) {
        __hip_atomic_fetch_add(&bar[slot], 1, __ATOMIC_RELEASE, __HIP_MEMORY_SCOPE_AGENT);
        while (__hip_atomic_load(&bar[slot], __ATOMIC_RELAXED, __HIP_MEMORY_SCOPE_AGENT) < NPB)
            __builtin_amdgcn_s_sleep(1);
    }
    __syncthreads();
}

// ---------------------------------------------------------------------------
// xprep: x fp32 NHWC -> padded bf16 [32][66][66][256]; block 0 zeroes ctrl.
// grid: 34848 x 256
// ---------------------------------------------------------------------------
__global__ __launch_bounds__(256) void k_xprep(const float* __restrict__ x,
                                               unsigned short* __restrict__ xb,
                                               float* __restrict__ ctrl) {
    int flat = blockIdx.x * 256 + threadIdx.x;
    int c4   = flat & 63;
    int rest = flat >> 6;                           // (b*66+hh)*66+ww
    int ww   = rest % 66;
    int r2   = rest / 66;
    int hh   = r2 % 66;
    int b    = r2 / 66;
    int h = hh - 1, w2 = ww - 1;
    ushort4 outv;
    if (h >= 0 && h < 64 && w2 >= 0 && w2 < 64) {
        const float4 v = *(const float4*)(x + ((((b << 6) + h) << 6) + w2) * 256 + (c4 << 2));
        outv.x = f2bf(v.x); outv.y = f2bf(v.y); outv.z = f2bf(v.z); outv.w = f2bf(v.w);
    } else {
        outv.x = 0; outv.y = 0; outv.z = 0; outv.w = 0;
    }
    *(ushort4*)(xb + ((size_t)rest << 8) + (c4 << 2)) = outv;
    if (blockIdx.x == 0 && threadIdx.x < 256) {     // zero bar/M/NA (first 512 floats)
        ctrl[threadIdx.x]       = 0.f;
        ctrl[threadIdx.x + 256] = 0.f;
    }
}

// ---------------------------------------------------------------------------
// k_power: entire 20-iteration power method + sigma + weight transform, fused.
// Cooperative launch: 64 blocks x 1024. thread=(o=bid*4+tid>>8, i=tid&255).
// kr[9] in VGPRs throughout; a,b,c,d,g in registers; cross-block M/pb/NA via
// agent atomics + gbar (2 barriers per iteration, 41 total).
// [r3-verbatim: measured 330us, VGPR 56, absmax 0.0625]
// ---------------------------------------------------------------------------
__global__ __launch_bounds__(1024) void k_power(const float* __restrict__ w,
                                                const float* __restrict__ u1,
                                                const float* __restrict__ u2,
                                                const float* __restrict__ u3,
                                                float* __restrict__ ctrl,
                                                unsigned short* __restrict__ wt3) {
    const int tid  = threadIdx.x, bid = blockIdx.x;
    const int os   = tid >> 8, i = tid & 255;
    const int lane = tid & 63, wid = tid >> 6;
    const int o    = (bid << 2) + os;

    int*                bar   = (int*)(ctrl + CTRL_BAR);
    unsigned long long* pbull = (unsigned long long*)(ctrl + CTRL_PB);

    __shared__ float red1[16];
    __shared__ c2    red2[16];
    __shared__ c2    abc[4];
    __shared__ float mred[16][18];
    __shared__ float nbshare;
    __shared__ float msm[18];
    __shared__ c2    shbuf[4][256];

    float kr[9];
    {
        const float* wr = w + (size_t)((o << 8) + i) * 9;
        #pragma unroll
        for (int j = 0; j < 9; ++j) kr[j] = wr[j];
    }

    c2 a_c = ((const c2*)u1)[o];
    c2 b_c = ((const c2*)u2)[i];
    c2 cprev[3];
    #pragma unroll
    for (int h = 0; h < 3; ++h) cprev[h] = ((const c2*)u3)[h];

    for (int t = 0; t <= 20; ++t) {
        // ---- M(t) accumulate into unique slot t (pre-zeroed by xprep) ----
        {
            c2 pc = cjg(cmul(a_c, b_c));
            float mv[18];
            #pragma unroll
            for (int hw = 0; hw < 9; ++hw) { mv[2 * hw] = kr[hw] * pc.x; mv[2 * hw + 1] = kr[hw] * pc.y; }
            #pragma unroll
            for (int j = 0; j < 18; ++j)
                #pragma unroll
                for (int off = 32; off; off >>= 1) mv[j] += __shfl_down(mv[j], off);
            if (lane == 0) {
                #pragma unroll
                for (int j = 0; j < 18; ++j) mred[wid][j] = mv[j];
            }
            __syncthreads();
            if (tid < 18) {
                float s3 = 0.f;
                #pragma unroll
                for (int k = 0; k < 16; ++k) s3 += mred[k][tid];
                aadd(ctrl + CTRL_M + t * 18 + tid, s3);
            }
        }
        if (t == 20 && i == 0)
            aadd(ctrl + CTRL_NA, a_c.x * a_c.x + a_c.y * a_c.y);
        gbar(bar, 2 * t, tid);
        // stage M(t) through LDS (18 agent loads per block, broadcast)
        if (tid < 18) msm[tid] = ald(ctrl + CTRL_M + t * 18 + tid);
        __syncthreads();
        if (t == 20) break;

        // ---- Q-part(t): d,c from M; g; pb ----
        float m[18];
        #pragma unroll
        for (int j = 0; j < 18; ++j) m[j] = msm[j];

        c2 dv[3]; float nd2 = 0.f;
        #pragma unroll
        for (int w2 = 0; w2 < 3; ++w2) {
            c2 s = {0.f, 0.f};
            #pragma unroll
            for (int h = 0; h < 3; ++h) {
                c2 mc = {m[2 * (h * 3 + w2)], m[2 * (h * 3 + w2) + 1]};
                s = cadd(s, cmul(mc, cjg(cprev[h])));
            }
            dv[w2] = s; nd2 += s.x * s.x + s.y * s.y;
        }
        {
            float inv = 1.f / (sqrtf(nd2) + EPSN);
            #pragma unroll
            for (int w2 = 0; w2 < 3; ++w2) dv[w2] = cscale(dv[w2], inv);
        }
        c2 cn[3]; float nc2 = 0.f;
        #pragma unroll
        for (int h = 0; h < 3; ++h) {
            c2 s = {0.f, 0.f};
            #pragma unroll
            for (int w2 = 0; w2 < 3; ++w2) {
                c2 mc = {m[2 * (h * 3 + w2)], m[2 * (h * 3 + w2) + 1]};
                s = cadd(s, cmul(mc, cjg(dv[w2])));
            }
            cn[h] = s; nc2 += s.x * s.x + s.y * s.y;
        }
        {
            float inv = 1.f / (sqrtf(nc2) + EPSN);
            #pragma unroll
            for (int h = 0; h < 3; ++h) cn[h] = cscale(cn[h], inv);
        }

        c2 g = {0.f, 0.f};
        #pragma unroll
        for (int h = 0; h < 3; ++h)
            #pragma unroll
            for (int w2 = 0; w2 < 3; ++w2) {
                c2 qv = cjg(cmul(cn[h], dv[w2]));
                g.x += kr[h * 3 + w2] * qv.x;
                g.y += kr[h * 3 + w2] * qv.y;
            }
        __syncthreads();
        shbuf[os][i] = cmul(cjg(a_c), g);
        __syncthreads();
        if (tid < 256) {
            c2 s = cadd(cadd(shbuf[0][tid], shbuf[1][tid]), cadd(shbuf[2][tid], shbuf[3][tid]));
            ast64(pbull + (bid << 8) + tid, s);
        }
        gbar(bar, 2 * t + 1, tid);

        // ---- P-part(t+1): b = N(sum_p pb); a = sum_i conj(b) g ----
        {
            c2 s = {0.f, 0.f};
            #pragma unroll 4
            for (int p = 0; p < 16; ++p)
                s = cadd(s, ald64(pbull + (((os << 4) + p) << 8) + i));
            __syncthreads();
            shbuf[os][i] = s;
        }
        __syncthreads();
        c2 bs = cadd(cadd(shbuf[0][i], shbuf[1][i]), cadd(shbuf[2][i], shbuf[3][i]));
        float n2 = bs.x * bs.x + bs.y * bs.y;      // 4 redundant copies per i
        #pragma unroll
        for (int off = 32; off; off >>= 1) n2 += __shfl_down(n2, off);
        if (lane == 0) red1[wid] = n2;
        __syncthreads();
        if (tid == 0) {
            float acc = 0.f;
            #pragma unroll
            for (int k = 0; k < 16; ++k) acc += red1[k];
            nbshare = sqrtf(acc * 0.25f);
        }
        __syncthreads();
        b_c = cscale(bs, 1.f / (nbshare + EPSN));

        c2 contrib = cmul(cjg(b_c), g);
        float vx = contrib.x, vy = contrib.y;
        #pragma unroll
        for (int off = 32; off; off >>= 1) { vx += __shfl_down(vx, off); vy += __shfl_down(vy, off); }
        if (lane == 0) red2[wid] = {vx, vy};
        __syncthreads();
        if (tid < 4) {
            c2 s2 = {0.f, 0.f};
            #pragma unroll
            for (int k = 0; k < 4; ++k) s2 = cadd(s2, red2[(tid << 2) + k]);
            abc[tid] = s2;
        }
        __syncthreads();
        a_c = abc[os];
        #pragma unroll
        for (int h = 0; h < 3; ++h) cprev[h] = cn[h];
    }

    // ---- tail: sigma; wt3[tap][o][ci] = bf16(w/sigma) ----
    float m[18];
    #pragma unroll
    for (int j = 0; j < 18; ++j) m[j] = msm[j];                  // M(20)
    c2 dv[3]; float nd2 = 0.f;
    #pragma unroll
    for (int w2 = 0; w2 < 3; ++w2) {
        c2 s = {0.f, 0.f};
        #pragma unroll
        for (int h = 0; h < 3; ++h) {
            c2 mc = {m[2 * (h * 3 + w2)], m[2 * (h * 3 + w2) + 1]};
            s = cadd(s, cmul(mc, cjg(cprev[h])));                 // cprev = c_19
        }
        dv[w2] = s; nd2 += s.x * s.x + s.y * s.y;
    }
    {
        float inv = 1.f / (sqrtf(nd2) + EPSN);
        #pragma unroll
        for (int w2 = 0; w2 < 3; ++w2) dv[w2] = cscale(dv[w2], inv);
    }
    c2 sg = {0.f, 0.f};
    #pragma unroll
    for (int h = 0; h < 3; ++h)
        #pragma unroll
        for (int w2 = 0; w2 < 3; ++w2) {
            c2 mc = {m[2 * (h * 3 + w2)], m[2 * (h * 3 + w2) + 1]};
            sg = cadd(sg, cmul(mc, cjg(cmul(cprev[h], dv[w2]))));
        }
    float na     = sqrtf(ald(ctrl + CTRL_NA));
    float invsig = (na + EPSN) / (sqrtf(sg.x * sg.x + sg.y * sg.y) + EPSN);
    #pragma unroll
    for (int tap = 0; tap < 9; ++tap)
        wt3[(size_t)tap * 65536 + (o << 8) + i] = f2bf(kr[tap] * invsig);
}

// ---------------------------------------------------------------------------
// conv v4: ZERO-LDS register implicit GEMM.
// Same geometry as v3: block = 128 pixels (2 rows x 64 cols) x 128 couts,
// 256 threads, 4 waves (2x2 of 64x64), 36 K-chunks (9 taps x 4 cc64).
// Per round each wave issues 16 per-lane global_load_dwordx4 gathers (the
// exact bytes the old LDS reads produced -> identical MFMA fragments) and
// 32 MFMAs. No __syncthreads, no LDS: loads pipeline freely across rounds;
// B (wt3 1.18MB) is L2-resident, A (xb) has 18x L2/LLC reuse.
// grid: 2048.  bid = (pixel_block<<1)|nb ; pixel_block = (b<<5)|hp
// ---------------------------------------------------------------------------
__global__ __launch_bounds__(256) void k_conv(const unsigned short* __restrict__ xb,
                                              const unsigned short* __restrict__ wt3,
                                              const float* __restrict__ bias,
                                              float* __restrict__ y) {
    const int tid  = threadIdx.x, bid = blockIdx.x;
    const int lane = tid & 63, wid = tid >> 6;
    const int l15  = lane & 15, q = lane >> 4;
    const int pbk  = bid >> 1, nb = bid & 1;
    const int b    = pbk >> 5, hp = pbk & 31, h0 = hp << 1;
    const int mh   = (wid & 1) << 6;
    const int nq   = (wid >> 1) << 6;
    const int n_off = (nb << 7) + nq;

    // per-lane fragment base offsets (ushort units)
    // A: pixel (mh+ms*16+l15) at channel q*8 ; B: cout (nq+ns*16+l15) at ci q*8
    int aL[4], bL[4];
    #pragma unroll
    for (int ms = 0; ms < 4; ++ms) {
        int pix = mh + (ms << 4) + l15;
        int r = pix >> 6, c = pix & 63;
        aL[ms] = ((b * 66 + h0 + r) * 66 + c) * 256 + (q << 3);
    }
    #pragma unroll
    for (int ns = 0; ns < 4; ++ns)
        bL[ns] = (nb << 15) + ((nq + (ns << 4) + l15) << 8) + (q << 3);

    f32x4 acc[4][4];
    #pragma unroll
    for (int ms = 0; ms < 4; ++ms)
        #pragma unroll
        for (int ns = 0; ns < 4; ++ns) acc[ms][ns] = {0.f, 0.f, 0.f, 0.f};

    #pragma unroll 1
    for (int tap = 0; tap < 9; ++tap) {
        const int kh = tap / 3, kw = tap % 3;
        const int aoff = (kh * 66 + kw) * 256;
        const int boff = tap << 16;
        #pragma unroll 1
        for (int cc = 0; cc < 4; ++cc) {
            const int ao = aoff + (cc << 6);
            const int bo = boff + (cc << 6);
            bf16x8 av[2][4], bv[2][4];
            #pragma unroll
            for (int ks = 0; ks < 2; ++ks) {
                #pragma unroll
                for (int ms = 0; ms < 4; ++ms)
                    av[ks][ms] = *(const bf16x8*)(xb + aL[ms] + ao + (ks << 5));
                #pragma unroll
                for (int ns = 0; ns < 4; ++ns)
                    bv[ks][ns] = *(const bf16x8*)(wt3 + bL[ns] + bo + (ks << 5));
            }
            #pragma unroll
            for (int ks = 0; ks < 2; ++ks)
                #pragma unroll
                for (int ms = 0; ms < 4; ++ms)
                    #pragma unroll
                    for (int ns = 0; ns < 4; ++ns)
                        acc[ms][ns] = __builtin_amdgcn_mfma_f32_16x16x32_bf16(
                            av[ks][ms], bv[ks][ns], acc[ms][ns], 0, 0, 0);
        }
    }

    float bias_v[4];
    #pragma unroll
    for (int ns = 0; ns < 4; ++ns) bias_v[ns] = bias[n_off + (ns << 4) + l15];

    #pragma unroll
    for (int ms = 0; ms < 4; ++ms) {
        const int pb2 = mh + (ms << 4) + (q << 2);
        #pragma unroll
        for (int r2 = 0; r2 < 4; ++r2) {
            const int pr = pb2 + r2;
            const int h = h0 + (pr >> 6), wc = pr & 63;
            float* yr = y + ((((b << 6) + h) << 6) + wc) * 256 + n_off;
            #pragma unroll
            for (int ns = 0; ns < 4; ++ns)
                yr[(ns << 4) + l15] = acc[ms][ns][r2] + bias_v[ns];
        }
    }
}

// ---------------------------------------------------------------------------
extern "C" void kernel_launch(void* const* d_in, const int* in_sizes, int n_in,
                              void* d_out, int out_size, void* d_ws, size_t ws_size,
                              hipStream_t stream) {
    const float* x    = (const float*)d_in[0];
    const float* w    = (const float*)d_in[1];
    const float* bias = (const float*)d_in[2];
    const float* u1   = (const float*)d_in[3];   // complex64 interleaved
    const float* u2   = (const float*)d_in[4];
    const float* u3   = (const float*)d_in[5];
    float* y = (float*)d_out;

    char* ws = (char*)d_ws;
    unsigned short* xb = (unsigned short*)(ws + XB_OFF);
    unsigned short* wt = (unsigned short*)(ws + WT_OFF);
    float*          ct = (float*)(ws + CTRL_OFF);

    k_xprep<<<34848, 256, 0, stream>>>(x, xb, ct);

    void* args[] = {(void*)&w, (void*)&u1, (void*)&u2, (void*)&u3, (void*)&ct, (void*)&wt};
    hipLaunchCooperativeKernel((const void*)k_power, dim3(NPB), dim3(1024), args, 0, stream);

    k_conv<<<2048, 256, 0, stream>>>(xb, wt, bias, y);
}

// Round 6
// 696.475 us; speedup vs baseline: 1.7090x; 1.5518x over previous
//
#include <hip/hip_runtime.h>
#include <math.h>

// ---------------------------------------------------------------------------
// SpectralConv2d: sigma = tensor-spectral-norm(w) via 20 complex power its,
// then y = conv2d_same(x, w/sigma, NHWC, 3x3) + bias.
// B=32 H=W=64 CIN=COUT=256 KH=KW=3.
// Round 9: conv v5 — halo-staged LDS implicit GEMM + XCD swizzle.
//   Diagnosis (r5 counters): conv was L2-thrashing (FETCH 547MB vs 72MB
//   input, MfmaUtil 12%). Fix: stage A halo (4 rows x 66 cols x 64ch,
//   33.8KB) ONCE per cc-chunk and serve all 9 taps from it (A staging
//   590->135 KB/block); bijective XCD swizzle so each XCD works 4
//   contiguous images (A working set 2.2MB < 4MB L2).
//   Fragment-read keeps v3's proven 64B-pixel-stride LDS pattern.
// k_power: r3-verbatim (330us proven). xprep unchanged.
// ---------------------------------------------------------------------------

#define EPSN 1e-12f

// ---- workspace layout (bytes) ----
// xb  : bf16 padded input  [32][66][66][256]          = 71,368,704 B
// wt3 : bf16 weights       [9tap][256cout][256ci]     =  1,179,648 B
// ctrl: float control area (33792 floats)             =    135,168 B
#define XB_OFF   0
#define WT_OFF   71368704
#define CTRL_OFF 72548352

// ctrl offsets (floats). All cross-block data accessed via AGENT-scope
// atomics only (coherent at LLC; per-XCD L2s never hold it).
#define CTRL_BAR 0      // int bar[64]   barrier arrival slots (one per sync)
#define CTRL_M   64     // M[21][18]     unique slot per iteration
#define CTRL_NA  448    // sum |a|^2
#define CTRL_PB  1024   // pb[64][256] complex (overwrite-only, no zeroing)

#define NPB 64          // power-kernel blocks

struct c2 { float x, y; };
__device__ inline c2 cadd(c2 a, c2 b) { return {a.x + b.x, a.y + b.y}; }
__device__ inline c2 cmul(c2 a, c2 b) { return {a.x * b.x - a.y * b.y, a.x * b.y + a.y * b.x}; }
__device__ inline c2 cjg(c2 a) { return {a.x, -a.y}; }
__device__ inline c2 cscale(c2 a, float s) { return {a.x * s, a.y * s}; }

__device__ inline unsigned short f2bf(float f) {  // RNE fp32->bf16
    unsigned int u = __float_as_uint(f);
    unsigned int r = u + 0x7fffu + ((u >> 16) & 1u);
    return (unsigned short)(r >> 16);
}

typedef __bf16 bf16x8 __attribute__((ext_vector_type(8)));
typedef float  f32x4  __attribute__((ext_vector_type(4)));

__device__ __forceinline__ void gl_lds16(const unsigned short* g, unsigned short* l) {
    __builtin_amdgcn_global_load_lds(
        (const __attribute__((address_space(1))) unsigned int*)g,
        (__attribute__((address_space(3))) unsigned int*)l, 16, 0, 0);
}

// agent-scope helpers (bypass non-coherent L2, live at LLC)
__device__ __forceinline__ float ald(const float* p) {
    return __hip_atomic_load(p, __ATOMIC_RELAXED, __HIP_MEMORY_SCOPE_AGENT);
}
__device__ __forceinline__ void aadd(float* p, float v) {
    __hip_atomic_fetch_add(p, v, __ATOMIC_RELAXED, __HIP_MEMORY_SCOPE_AGENT);
}
__device__ __forceinline__ void ast64(unsigned long long* p, c2 v) {
    union { c2 c; unsigned long long u; } cv; cv.c = v;
    __hip_atomic_store(p, cv.u, __ATOMIC_RELAXED, __HIP_MEMORY_SCOPE_AGENT);
}
__device__ __forceinline__ c2 ald64(const unsigned long long* p) {
    union { c2 c; unsigned long long u; } cv;
    cv.u = __hip_atomic_load(p, __ATOMIC_RELAXED, __HIP_MEMORY_SCOPE_AGENT);
    return cv.c;
}

// Device barrier over NPB blocks. Requires co-residency (cooperative launch).
__device__ __forceinline__ void gbar(int* bar, int slot, int tid) {
    __syncthreads();
    if (tid == 0) {
        __hip_atomic_fetch_add(&bar[slot], 1, __ATOMIC_RELEASE, __HIP_MEMORY_SCOPE_AGENT);
        while (__hip_atomic_load(&bar[slot], __ATOMIC_RELAXED, __HIP_MEMORY_SCOPE_AGENT) < NPB)
            __builtin_amdgcn_s_sleep(1);
    }
    __syncthreads();
}

// ---------------------------------------------------------------------------
// xprep: x fp32 NHWC -> padded bf16 [32][66][66][256]; block 0 zeroes ctrl.
// grid: 34848 x 256
// ---------------------------------------------------------------------------
__global__ __launch_bounds__(256) void k_xprep(const float* __restrict__ x,
                                               unsigned short* __restrict__ xb,
                                               float* __restrict__ ctrl) {
    int flat = blockIdx.x * 256 + threadIdx.x;
    int c4   = flat & 63;
    int rest = flat >> 6;                           // (b*66+hh)*66+ww
    int ww   = rest % 66;
    int r2   = rest / 66;
    int hh   = r2 % 66;
    int b    = r2 / 66;
    int h = hh - 1, w2 = ww - 1;
    ushort4 outv;
    if (h >= 0 && h < 64 && w2 >= 0 && w2 < 64) {
        const float4 v = *(const float4*)(x + ((((b << 6) + h) << 6) + w2) * 256 + (c4 << 2));
        outv.x = f2bf(v.x); outv.y = f2bf(v.y); outv.z = f2bf(v.z); outv.w = f2bf(v.w);
    } else {
        outv.x = 0; outv.y = 0; outv.z = 0; outv.w = 0;
    }
    *(ushort4*)(xb + ((size_t)rest << 8) + (c4 << 2)) = outv;
    if (blockIdx.x == 0 && threadIdx.x < 256) {     // zero bar/M/NA (first 512 floats)
        ctrl[threadIdx.x]       = 0.f;
        ctrl[threadIdx.x + 256] = 0.f;
    }
}

// ---------------------------------------------------------------------------
// k_power: entire 20-iteration power method + sigma + weight transform, fused.
// Cooperative launch: 64 blocks x 1024. thread=(o=bid*4+tid>>8, i=tid&255).
// [r3-verbatim: measured 330us, VGPR 56, absmax 0.0625]
// ---------------------------------------------------------------------------
__global__ __launch_bounds__(1024) void k_power(const float* __restrict__ w,
                                                const float* __restrict__ u1,
                                                const float* __restrict__ u2,
                                                const float* __restrict__ u3,
                                                float* __restrict__ ctrl,
                                                unsigned short* __restrict__ wt3) {
    const int tid  = threadIdx.x, bid = blockIdx.x;
    const int os   = tid >> 8, i = tid & 255;
    const int lane = tid & 63, wid = tid >> 6;
    const int o    = (bid << 2) + os;

    int*                bar   = (int*)(ctrl + CTRL_BAR);
    unsigned long long* pbull = (unsigned long long*)(ctrl + CTRL_PB);

    __shared__ float red1[16];
    __shared__ c2    red2[16];
    __shared__ c2    abc[4];
    __shared__ float mred[16][18];
    __shared__ float nbshare;
    __shared__ float msm[18];
    __shared__ c2    shbuf[4][256];

    float kr[9];
    {
        const float* wr = w + (size_t)((o << 8) + i) * 9;
        #pragma unroll
        for (int j = 0; j < 9; ++j) kr[j] = wr[j];
    }

    c2 a_c = ((const c2*)u1)[o];
    c2 b_c = ((const c2*)u2)[i];
    c2 cprev[3];
    #pragma unroll
    for (int h = 0; h < 3; ++h) cprev[h] = ((const c2*)u3)[h];

    for (int t = 0; t <= 20; ++t) {
        // ---- M(t) accumulate into unique slot t (pre-zeroed by xprep) ----
        {
            c2 pc = cjg(cmul(a_c, b_c));
            float mv[18];
            #pragma unroll
            for (int hw = 0; hw < 9; ++hw) { mv[2 * hw] = kr[hw] * pc.x; mv[2 * hw + 1] = kr[hw] * pc.y; }
            #pragma unroll
            for (int j = 0; j < 18; ++j)
                #pragma unroll
                for (int off = 32; off; off >>= 1) mv[j] += __shfl_down(mv[j], off);
            if (lane == 0) {
                #pragma unroll
                for (int j = 0; j < 18; ++j) mred[wid][j] = mv[j];
            }
            __syncthreads();
            if (tid < 18) {
                float s3 = 0.f;
                #pragma unroll
                for (int k = 0; k < 16; ++k) s3 += mred[k][tid];
                aadd(ctrl + CTRL_M + t * 18 + tid, s3);
            }
        }
        if (t == 20 && i == 0)
            aadd(ctrl + CTRL_NA, a_c.x * a_c.x + a_c.y * a_c.y);
        gbar(bar, 2 * t, tid);
        // stage M(t) through LDS (18 agent loads per block, broadcast)
        if (tid < 18) msm[tid] = ald(ctrl + CTRL_M + t * 18 + tid);
        __syncthreads();
        if (t == 20) break;

        // ---- Q-part(t): d,c from M; g; pb ----
        float m[18];
        #pragma unroll
        for (int j = 0; j < 18; ++j) m[j] = msm[j];

        c2 dv[3]; float nd2 = 0.f;
        #pragma unroll
        for (int w2 = 0; w2 < 3; ++w2) {
            c2 s = {0.f, 0.f};
            #pragma unroll
            for (int h = 0; h < 3; ++h) {
                c2 mc = {m[2 * (h * 3 + w2)], m[2 * (h * 3 + w2) + 1]};
                s = cadd(s, cmul(mc, cjg(cprev[h])));
            }
            dv[w2] = s; nd2 += s.x * s.x + s.y * s.y;
        }
        {
            float inv = 1.f / (sqrtf(nd2) + EPSN);
            #pragma unroll
            for (int w2 = 0; w2 < 3; ++w2) dv[w2] = cscale(dv[w2], inv);
        }
        c2 cn[3]; float nc2 = 0.f;
        #pragma unroll
        for (int h = 0; h < 3; ++h) {
            c2 s = {0.f, 0.f};
            #pragma unroll
            for (int w2 = 0; w2 < 3; ++w2) {
                c2 mc = {m[2 * (h * 3 + w2)], m[2 * (h * 3 + w2) + 1]};
                s = cadd(s, cmul(mc, cjg(dv[w2])));
            }
            cn[h] = s; nc2 += s.x * s.x + s.y * s.y;
        }
        {
            float inv = 1.f / (sqrtf(nc2) + EPSN);
            #pragma unroll
            for (int h = 0; h < 3; ++h) cn[h] = cscale(cn[h], inv);
        }

        c2 g = {0.f, 0.f};
        #pragma unroll
        for (int h = 0; h < 3; ++h)
            #pragma unroll
            for (int w2 = 0; w2 < 3; ++w2) {
                c2 qv = cjg(cmul(cn[h], dv[w2]));
                g.x += kr[h * 3 + w2] * qv.x;
                g.y += kr[h * 3 + w2] * qv.y;
            }
        __syncthreads();
        shbuf[os][i] = cmul(cjg(a_c), g);
        __syncthreads();
        if (tid < 256) {
            c2 s = cadd(cadd(shbuf[0][tid], shbuf[1][tid]), cadd(shbuf[2][tid], shbuf[3][tid]));
            ast64(pbull + (bid << 8) + tid, s);
        }
        gbar(bar, 2 * t + 1, tid);

        // ---- P-part(t+1): b = N(sum_p pb); a = sum_i conj(b) g ----
        {
            c2 s = {0.f, 0.f};
            #pragma unroll 4
            for (int p = 0; p < 16; ++p)
                s = cadd(s, ald64(pbull + (((os << 4) + p) << 8) + i));
            __syncthreads();
            shbuf[os][i] = s;
        }
        __syncthreads();
        c2 bs = cadd(cadd(shbuf[0][i], shbuf[1][i]), cadd(shbuf[2][i], shbuf[3][i]));
        float n2 = bs.x * bs.x + bs.y * bs.y;      // 4 redundant copies per i
        #pragma unroll
        for (int off = 32; off; off >>= 1) n2 += __shfl_down(n2, off);
        if (lane == 0) red1[wid] = n2;
        __syncthreads();
        if (tid == 0) {
            float acc = 0.f;
            #pragma unroll
            for (int k = 0; k < 16; ++k) acc += red1[k];
            nbshare = sqrtf(acc * 0.25f);
        }
        __syncthreads();
        b_c = cscale(bs, 1.f / (nbshare + EPSN));

        c2 contrib = cmul(cjg(b_c), g);
        float vx = contrib.x, vy = contrib.y;
        #pragma unroll
        for (int off = 32; off; off >>= 1) { vx += __shfl_down(vx, off); vy += __shfl_down(vy, off); }
        if (lane == 0) red2[wid] = {vx, vy};
        __syncthreads();
        if (tid < 4) {
            c2 s2 = {0.f, 0.f};
            #pragma unroll
            for (int k = 0; k < 4; ++k) s2 = cadd(s2, red2[(tid << 2) + k]);
            abc[tid] = s2;
        }
        __syncthreads();
        a_c = abc[os];
        #pragma unroll
        for (int h = 0; h < 3; ++h) cprev[h] = cn[h];
    }

    // ---- tail: sigma; wt3[tap][o][ci] = bf16(w/sigma) ----
    float m[18];
    #pragma unroll
    for (int j = 0; j < 18; ++j) m[j] = msm[j];                  // M(20)
    c2 dv[3]; float nd2 = 0.f;
    #pragma unroll
    for (int w2 = 0; w2 < 3; ++w2) {
        c2 s = {0.f, 0.f};
        #pragma unroll
        for (int h = 0; h < 3; ++h) {
            c2 mc = {m[2 * (h * 3 + w2)], m[2 * (h * 3 + w2) + 1]};
            s = cadd(s, cmul(mc, cjg(cprev[h])));                 // cprev = c_19
        }
        dv[w2] = s; nd2 += s.x * s.x + s.y * s.y;
    }
    {
        float inv = 1.f / (sqrtf(nd2) + EPSN);
        #pragma unroll
        for (int w2 = 0; w2 < 3; ++w2) dv[w2] = cscale(dv[w2], inv);
    }
    c2 sg = {0.f, 0.f};
    #pragma unroll
    for (int h = 0; h < 3; ++h)
        #pragma unroll
        for (int w2 = 0; w2 < 3; ++w2) {
            c2 mc = {m[2 * (h * 3 + w2)], m[2 * (h * 3 + w2) + 1]};
            sg = cadd(sg, cmul(mc, cjg(cmul(cprev[h], dv[w2]))));
        }
    float na     = sqrtf(ald(ctrl + CTRL_NA));
    float invsig = (na + EPSN) / (sqrtf(sg.x * sg.x + sg.y * sg.y) + EPSN);
    #pragma unroll
    for (int tap = 0; tap < 9; ++tap)
        wt3[(size_t)tap * 65536 + (o << 8) + i] = f2bf(kr[tap] * invsig);
}

// ---------------------------------------------------------------------------
// conv v5: halo-staged LDS implicit GEMM + XCD swizzle.
// Block = 128 pixels (2 rows x 64 cols) x 128 couts, 256 threads, 4 waves.
// Per cc64 chunk: stage A halo [2ks][4rows][66cols][32ch] (33.8KB) ONCE via
// 9 gl_lds/thread; then 9 taps each {16KB B stage + 32 MFMA/wave} read the
// SAME A tile at (kh,kw) offsets. A global traffic 590->135 KB/block.
// Fragment reads keep v3's proven 64B-pixel-stride LDS pattern.
// XCD swizzle: bid = (raw&7)*256 + raw>>3  (2048 = 8*256, bijective);
// each XCD works 4 contiguous images -> A set 2.2MB < 4MB L2.
// ---------------------------------------------------------------------------
__global__ __launch_bounds__(256) void k_conv(const unsigned short* __restrict__ xb,
                                              const unsigned short* __restrict__ wt3,
                                              const float* __restrict__ bias,
                                              float* __restrict__ y) {
    __shared__ unsigned short lA[16896];  // [2 ks][264 pix(4r x 66c)][32 ch]
    __shared__ unsigned short lB[8192];   // [2 ks][128 cout][32 ci]
    const int tid  = threadIdx.x;
    const int raw  = blockIdx.x;
    const int bid  = ((raw & 7) << 8) + (raw >> 3);   // XCD-contiguous chunks
    const int lane = tid & 63, wid = tid >> 6;
    const int l15  = lane & 15, q = lane >> 4;
    const int pbk  = bid >> 1, nb = bid & 1;
    const int b    = pbk >> 5, hp = pbk & 31, h0 = hp << 1;
    const int rw   = wid & 1;               // wave's pixel-row within block
    const int nq   = (wid >> 1) << 6;
    const int n_off = (nb << 7) + nq;

    // ---- A-stage addresses: unit u covers 8ch of halo pixel pixA ----
    // u in [0,2112): ks = u>=1056, pixA = (u%1056)>>2 (r'*66+c'), q4 = u&3
    int asrc[9];
    #pragma unroll
    for (int j = 0; j < 9; ++j) {
        int u    = (j < 8) ? ((j << 8) + tid) : (2048 + (tid & 63));
        int ks   = (u >= 1056) ? 1 : 0;
        int rem  = u - ks * 1056;
        int pixA = rem >> 2, q4 = rem & 3;
        int rr   = pixA / 66, cc2 = pixA - rr * 66;
        asrc[j] = ((b * 66 + h0 + rr) * 66 + cc2) * 256 + ks * 32 + q4 * 8;
    }
    // ---- B-stage addresses (v3-verbatim): unit u covers 8ci of cout ----
    int bg[4];
    #pragma unroll
    for (int j = 0; j < 4; ++j) {
        int u   = (j << 8) + tid;
        int ce  = ((u >> 9) << 5) + ((u & 3) << 3);
        bg[j] = (nb << 15) + (((u >> 2) & 127) << 8) + ce;
    }

    f32x4 acc[4][4];
    #pragma unroll
    for (int ms = 0; ms < 4; ++ms)
        #pragma unroll
        for (int ns = 0; ns < 4; ++ns) acc[ms][ns] = {0.f, 0.f, 0.f, 0.f};

    #pragma unroll 1
    for (int cc = 0; cc < 4; ++cc) {
        const int cco = cc << 6;
        // stage A halo once per cc (33.8KB) + B for tap 0
        #pragma unroll
        for (int j = 0; j < 8; ++j)
            gl_lds16(xb + asrc[j] + cco, lA + (j << 11) + (tid << 3));
        if (tid < 64)
            gl_lds16(xb + asrc[8] + cco, lA + 16384 + (tid << 3));
        #pragma unroll
        for (int j = 0; j < 4; ++j)
            gl_lds16(wt3 + bg[j] + cco, lB + (j << 11) + (tid << 3));
        __syncthreads();

        #pragma unroll 1
        for (int tap = 0; tap < 9; ++tap) {
            const int kh = tap / 3, kw = tap % 3;
            const int arow = ((rw + kh) * 66 + kw) << 5;   // ushort offset base
            #pragma unroll
            for (int ks = 0; ks < 2; ++ks) {
                bf16x8 av[4], bv[4];
                #pragma unroll
                for (int ms = 0; ms < 4; ++ms)
                    av[ms] = *(const bf16x8*)(lA + ks * 8448 + arow + (((ms << 4) + l15) << 5) + (q << 3));
                #pragma unroll
                for (int ns = 0; ns < 4; ++ns)
                    bv[ns] = *(const bf16x8*)(lB + (ks << 12) + ((nq + (ns << 4) + l15) << 5) + (q << 3));
                #pragma unroll
                for (int ms = 0; ms < 4; ++ms)
                    #pragma unroll
                    for (int ns = 0; ns < 4; ++ns)
                        acc[ms][ns] = __builtin_amdgcn_mfma_f32_16x16x32_bf16(
                            av[ms], bv[ns], acc[ms][ns], 0, 0, 0);
            }
            __syncthreads();                       // B reads done (all waves)
            if (tap < 8) {
                #pragma unroll
                for (int j = 0; j < 4; ++j)
                    gl_lds16(wt3 + bg[j] + ((tap + 1) << 16) + cco, lB + (j << 11) + (tid << 3));
                __syncthreads();                   // B(tap+1) staged (vmcnt drained)
            }
        }
    }

    float bias_v[4];
    #pragma unroll
    for (int ns = 0; ns < 4; ++ns) bias_v[ns] = bias[n_off + (ns << 4) + l15];

    const int mh = rw << 6;
    #pragma unroll
    for (int ms = 0; ms < 4; ++ms) {
        const int pb2 = mh + (ms << 4) + (q << 2);
        #pragma unroll
        for (int r2 = 0; r2 < 4; ++r2) {
            const int pr = pb2 + r2;
            const int h = h0 + (pr >> 6), wc = pr & 63;
            float* yr = y + ((((b << 6) + h) << 6) + wc) * 256 + n_off;
            #pragma unroll
            for (int ns = 0; ns < 4; ++ns)
                yr[(ns << 4) + l15] = acc[ms][ns][r2] + bias_v[ns];
        }
    }
}

// ---------------------------------------------------------------------------
extern "C" void kernel_launch(void* const* d_in, const int* in_sizes, int n_in,
                              void* d_out, int out_size, void* d_ws, size_t ws_size,
                              hipStream_t stream) {
    const float* x    = (const float*)d_in[0];
    const float* w    = (const float*)d_in[1];
    const float* bias = (const float*)d_in[2];
    const float* u1   = (const float*)d_in[3];   // complex64 interleaved
    const float* u2   = (const float*)d_in[4];
    const float* u3   = (const float*)d_in[5];
    float* y = (float*)d_out;

    char* ws = (char*)d_ws;
    unsigned short* xb = (unsigned short*)(ws + XB_OFF);
    unsigned short* wt = (unsigned short*)(ws + WT_OFF);
    float*          ct = (float*)(ws + CTRL_OFF);

    k_xprep<<<34848, 256, 0, stream>>>(x, xb, ct);

    void* args[] = {(void*)&w, (void*)&u1, (void*)&u2, (void*)&u3, (void*)&ct, (void*)&wt};
    hipLaunchCooperativeKernel((const void*)k_power, dim3(NPB), dim3(1024), args, 0, stream);

    k_conv<<<2048, 256, 0, stream>>>(xb, wt, bias, y);
}

// Round 7
// 603.735 us; speedup vs baseline: 1.9716x; 1.1536x over previous
//
#include <hip/hip_runtime.h>
#include <math.h>

// ---------------------------------------------------------------------------
// SpectralConv2d: sigma = tensor-spectral-norm(w) via 20 complex power its,
// then y = conv2d_same(x, w/sigma, NHWC, 3x3) + bias.
// B=32 H=W=64 CIN=COUT=256 KH=KW=3.
// Round 10: OVERLAP power with conv. Algebra: y = conv(x,w)*invsig + bias,
// so conv uses UNNORMALIZED bf16(w) (prepped by xprep) and runs concurrently
// with the power iteration in ONE fused kernel:
//   - bids 0..63   : r3-verbatim power (1024 thr), publishes invsig only
//   - bids 64..575 : conv blocks, 4 rows x 256 couts, 16 waves, A-halo
//                    staged once per cc64, B double-buffered (1 barrier/tap)
// Regular launch (NOT cooperative): conv blocks never wait -> power's 64
// blocks eventually co-resident regardless of dispatch order (deadlock-free);
// in-order dispatch gives the overlap. k_scale epilogue: y = y*invsig + bias.
// ---------------------------------------------------------------------------

#define EPSN 1e-12f

// ---- workspace layout (bytes) ----
// xb  : bf16 padded input  [32][66][66][256]          = 71,368,704 B
// wt3u: bf16 UNNORMALIZED  [9tap][256cout][256ci]     =  1,179,648 B
// ctrl: float control area (33792 floats)             =    135,168 B
#define XB_OFF   0
#define WT_OFF   71368704
#define CTRL_OFF 72548352

#define CTRL_BAR 0      // int bar[64]   barrier arrival slots (one per sync)
#define CTRL_M   64     // M[21][18]     unique slot per iteration
#define CTRL_NA  448    // sum |a|^2
#define CTRL_SIG 456    // invsig (published by power block 0)
#define CTRL_PB  1024   // pb[64][256] complex (overwrite-only, no zeroing)

#define NPB 64          // power blocks (bids 0..63 of k_fused)

struct c2 { float x, y; };
__device__ inline c2 cadd(c2 a, c2 b) { return {a.x + b.x, a.y + b.y}; }
__device__ inline c2 cmul(c2 a, c2 b) { return {a.x * b.x - a.y * b.y, a.x * b.y + a.y * b.x}; }
__device__ inline c2 cjg(c2 a) { return {a.x, -a.y}; }
__device__ inline c2 cscale(c2 a, float s) { return {a.x * s, a.y * s}; }

__device__ inline unsigned short f2bf(float f) {  // RNE fp32->bf16
    unsigned int u = __float_as_uint(f);
    unsigned int r = u + 0x7fffu + ((u >> 16) & 1u);
    return (unsigned short)(r >> 16);
}

typedef __bf16 bf16x8 __attribute__((ext_vector_type(8)));
typedef float  f32x4  __attribute__((ext_vector_type(4)));

__device__ __forceinline__ void gl_lds16(const unsigned short* g, unsigned short* l) {
    __builtin_amdgcn_global_load_lds(
        (const __attribute__((address_space(1))) unsigned int*)g,
        (__attribute__((address_space(3))) unsigned int*)l, 16, 0, 0);
}

// agent-scope helpers (bypass non-coherent L2, live at LLC)
__device__ __forceinline__ float ald(const float* p) {
    return __hip_atomic_load(p, __ATOMIC_RELAXED, __HIP_MEMORY_SCOPE_AGENT);
}
__device__ __forceinline__ void aadd(float* p, float v) {
    __hip_atomic_fetch_add(p, v, __ATOMIC_RELAXED, __HIP_MEMORY_SCOPE_AGENT);
}
__device__ __forceinline__ void ast32(float* p, float v) {
    __hip_atomic_store(p, v, __ATOMIC_RELAXED, __HIP_MEMORY_SCOPE_AGENT);
}
__device__ __forceinline__ void ast64(unsigned long long* p, c2 v) {
    union { c2 c; unsigned long long u; } cv; cv.c = v;
    __hip_atomic_store(p, cv.u, __ATOMIC_RELAXED, __HIP_MEMORY_SCOPE_AGENT);
}
__device__ __forceinline__ c2 ald64(const unsigned long long* p) {
    union { c2 c; unsigned long long u; } cv;
    cv.u = __hip_atomic_load(p, __ATOMIC_RELAXED, __HIP_MEMORY_SCOPE_AGENT);
    return cv.c;
}

// Device barrier over the NPB power blocks. Safe without cooperative launch:
// the other (conv) blocks never wait on power, so they drain and free slots
// until all NPB power blocks are co-resident; then arrivals complete.
__device__ __forceinline__ void gbar(int* bar, int slot, int tid) {
    __syncthreads();
    if (tid == 0) {
        __hip_atomic_fetch_add(&bar[slot], 1, __ATOMIC_RELEASE, __HIP_MEMORY_SCOPE_AGENT);
        while (__hip_atomic_load(&bar[slot], __ATOMIC_RELAXED, __HIP_MEMORY_SCOPE_AGENT) < NPB)
            __builtin_amdgcn_s_sleep(1);
    }
    __syncthreads();
}

// ---------------------------------------------------------------------------
// xprep: x fp32 NHWC -> padded bf16 [32][66][66][256]; block 0 zeroes ctrl;
// blocks >= 34848 write wt3u[tap][o][ci] = bf16(w) (unnormalized).
// grid: 35104 x 256
// ---------------------------------------------------------------------------
__global__ __launch_bounds__(256) void k_xprep(const float* __restrict__ x,
                                               unsigned short* __restrict__ xb,
                                               float* __restrict__ ctrl,
                                               const float* __restrict__ w,
                                               unsigned short* __restrict__ wt3u) {
    const int bid = blockIdx.x;
    if (bid >= 34848) {                              // weight prep: 256 blocks
        int pair = ((bid - 34848) << 8) + threadIdx.x;   // o*256 + ci
        const float* wr = w + (size_t)pair * 9;
        #pragma unroll
        for (int j = 0; j < 9; ++j)
            wt3u[j * 65536 + pair] = f2bf(wr[j]);
        return;
    }
    int flat = bid * 256 + threadIdx.x;
    int c4   = flat & 63;
    int rest = flat >> 6;                           // (b*66+hh)*66+ww
    int ww   = rest % 66;
    int r2   = rest / 66;
    int hh   = r2 % 66;
    int b    = r2 / 66;
    int h = hh - 1, w2 = ww - 1;
    ushort4 outv;
    if (h >= 0 && h < 64 && w2 >= 0 && w2 < 64) {
        const float4 v = *(const float4*)(x + ((((b << 6) + h) << 6) + w2) * 256 + (c4 << 2));
        outv.x = f2bf(v.x); outv.y = f2bf(v.y); outv.z = f2bf(v.z); outv.w = f2bf(v.w);
    } else {
        outv.x = 0; outv.y = 0; outv.z = 0; outv.w = 0;
    }
    *(ushort4*)(xb + ((size_t)rest << 8) + (c4 << 2)) = outv;
    if (bid == 0 && threadIdx.x < 256) {            // zero bar/M/NA/SIG
        ctrl[threadIdx.x]       = 0.f;
        ctrl[threadIdx.x + 256] = 0.f;
    }
}

// ---------------------------------------------------------------------------
// k_fused: power (bids 0..63, r3-verbatim transport) + conv (bids 64..575).
// 1024 threads/block. Power publishes invsig to ctrl[CTRL_SIG].
// Conv block: image b, output rows h0..h0+3, all 256 couts. 16 waves as
// 4(row) x 4(cout64). Per cc64: A halo [2ks][6r*66c][32ch] (50.7KB) staged
// once; B [2ks][256cout][32ci] (32.8KB) double-buffered per tap.
// Writes UNSCALED y (no bias) -> k_scale finishes.
// ---------------------------------------------------------------------------
__global__ __launch_bounds__(1024, 4) void k_fused(const unsigned short* __restrict__ xb,
                                                   const unsigned short* __restrict__ wt3u,
                                                   const float* __restrict__ w,
                                                   const float* __restrict__ u1,
                                                   const float* __restrict__ u2,
                                                   const float* __restrict__ u3,
                                                   float* __restrict__ ctrl,
                                                   float* __restrict__ y) {
    const int tid = threadIdx.x;

    if (blockIdx.x < NPB) {
        // =================== POWER PATH (r3-verbatim transport) ===========
        const int bid  = blockIdx.x;
        const int os   = tid >> 8, i = tid & 255;
        const int lane = tid & 63, wid = tid >> 6;
        const int o    = (bid << 2) + os;

        int*                bar   = (int*)(ctrl + CTRL_BAR);
        unsigned long long* pbull = (unsigned long long*)(ctrl + CTRL_PB);

        __shared__ float red1[16];
        __shared__ c2    red2[16];
        __shared__ c2    abc[4];
        __shared__ float mred[16][18];
        __shared__ float nbshare;
        __shared__ float msm[18];
        __shared__ c2    shbuf[4][256];

        float kr[9];
        {
            const float* wr = w + (size_t)((o << 8) + i) * 9;
            #pragma unroll
            for (int j = 0; j < 9; ++j) kr[j] = wr[j];
        }

        c2 a_c = ((const c2*)u1)[o];
        c2 b_c = ((const c2*)u2)[i];
        c2 cprev[3];
        #pragma unroll
        for (int h = 0; h < 3; ++h) cprev[h] = ((const c2*)u3)[h];

        for (int t = 0; t <= 20; ++t) {
            {
                c2 pc = cjg(cmul(a_c, b_c));
                float mv[18];
                #pragma unroll
                for (int hw = 0; hw < 9; ++hw) { mv[2 * hw] = kr[hw] * pc.x; mv[2 * hw + 1] = kr[hw] * pc.y; }
                #pragma unroll
                for (int j = 0; j < 18; ++j)
                    #pragma unroll
                    for (int off = 32; off; off >>= 1) mv[j] += __shfl_down(mv[j], off);
                if (lane == 0) {
                    #pragma unroll
                    for (int j = 0; j < 18; ++j) mred[wid][j] = mv[j];
                }
                __syncthreads();
                if (tid < 18) {
                    float s3 = 0.f;
                    #pragma unroll
                    for (int k = 0; k < 16; ++k) s3 += mred[k][tid];
                    aadd(ctrl + CTRL_M + t * 18 + tid, s3);
                }
            }
            if (t == 20 && i == 0)
                aadd(ctrl + CTRL_NA, a_c.x * a_c.x + a_c.y * a_c.y);
            gbar(bar, 2 * t, tid);
            if (tid < 18) msm[tid] = ald(ctrl + CTRL_M + t * 18 + tid);
            __syncthreads();
            if (t == 20) break;

            float m[18];
            #pragma unroll
            for (int j = 0; j < 18; ++j) m[j] = msm[j];

            c2 dv[3]; float nd2 = 0.f;
            #pragma unroll
            for (int w2 = 0; w2 < 3; ++w2) {
                c2 s = {0.f, 0.f};
                #pragma unroll
                for (int h = 0; h < 3; ++h) {
                    c2 mc = {m[2 * (h * 3 + w2)], m[2 * (h * 3 + w2) + 1]};
                    s = cadd(s, cmul(mc, cjg(cprev[h])));
                }
                dv[w2] = s; nd2 += s.x * s.x + s.y * s.y;
            }
            {
                float inv = 1.f / (sqrtf(nd2) + EPSN);
                #pragma unroll
                for (int w2 = 0; w2 < 3; ++w2) dv[w2] = cscale(dv[w2], inv);
            }
            c2 cn[3]; float nc2 = 0.f;
            #pragma unroll
            for (int h = 0; h < 3; ++h) {
                c2 s = {0.f, 0.f};
                #pragma unroll
                for (int w2 = 0; w2 < 3; ++w2) {
                    c2 mc = {m[2 * (h * 3 + w2)], m[2 * (h * 3 + w2) + 1]};
                    s = cadd(s, cmul(mc, cjg(dv[w2])));
                }
                cn[h] = s; nc2 += s.x * s.x + s.y * s.y;
            }
            {
                float inv = 1.f / (sqrtf(nc2) + EPSN);
                #pragma unroll
                for (int h = 0; h < 3; ++h) cn[h] = cscale(cn[h], inv);
            }

            c2 g = {0.f, 0.f};
            #pragma unroll
            for (int h = 0; h < 3; ++h)
                #pragma unroll
                for (int w2 = 0; w2 < 3; ++w2) {
                    c2 qv = cjg(cmul(cn[h], dv[w2]));
                    g.x += kr[h * 3 + w2] * qv.x;
                    g.y += kr[h * 3 + w2] * qv.y;
                }
            __syncthreads();
            shbuf[os][i] = cmul(cjg(a_c), g);
            __syncthreads();
            if (tid < 256) {
                c2 s = cadd(cadd(shbuf[0][tid], shbuf[1][tid]), cadd(shbuf[2][tid], shbuf[3][tid]));
                ast64(pbull + (bid << 8) + tid, s);
            }
            gbar(bar, 2 * t + 1, tid);

            {
                c2 s = {0.f, 0.f};
                #pragma unroll 4
                for (int p = 0; p < 16; ++p)
                    s = cadd(s, ald64(pbull + (((os << 4) + p) << 8) + i));
                __syncthreads();
                shbuf[os][i] = s;
            }
            __syncthreads();
            c2 bs = cadd(cadd(shbuf[0][i], shbuf[1][i]), cadd(shbuf[2][i], shbuf[3][i]));
            float n2 = bs.x * bs.x + bs.y * bs.y;
            #pragma unroll
            for (int off = 32; off; off >>= 1) n2 += __shfl_down(n2, off);
            if (lane == 0) red1[wid] = n2;
            __syncthreads();
            if (tid == 0) {
                float acc2 = 0.f;
                #pragma unroll
                for (int k = 0; k < 16; ++k) acc2 += red1[k];
                nbshare = sqrtf(acc2 * 0.25f);
            }
            __syncthreads();
            b_c = cscale(bs, 1.f / (nbshare + EPSN));

            c2 contrib = cmul(cjg(b_c), g);
            float vx = contrib.x, vy = contrib.y;
            #pragma unroll
            for (int off = 32; off; off >>= 1) { vx += __shfl_down(vx, off); vy += __shfl_down(vy, off); }
            if (lane == 0) red2[wid] = {vx, vy};
            __syncthreads();
            if (tid < 4) {
                c2 s2 = {0.f, 0.f};
                #pragma unroll
                for (int k = 0; k < 4; ++k) s2 = cadd(s2, red2[(tid << 2) + k]);
                abc[tid] = s2;
            }
            __syncthreads();
            a_c = abc[os];
            #pragma unroll
            for (int h = 0; h < 3; ++h) cprev[h] = cn[h];
        }

        // tail: sigma -> invsig publish
        float m[18];
        #pragma unroll
        for (int j = 0; j < 18; ++j) m[j] = msm[j];
        c2 dv[3]; float nd2 = 0.f;
        #pragma unroll
        for (int w2 = 0; w2 < 3; ++w2) {
            c2 s = {0.f, 0.f};
            #pragma unroll
            for (int h = 0; h < 3; ++h) {
                c2 mc = {m[2 * (h * 3 + w2)], m[2 * (h * 3 + w2) + 1]};
                s = cadd(s, cmul(mc, cjg(cprev[h])));
            }
            dv[w2] = s; nd2 += s.x * s.x + s.y * s.y;
        }
        {
            float inv = 1.f / (sqrtf(nd2) + EPSN);
            #pragma unroll
            for (int w2 = 0; w2 < 3; ++w2) dv[w2] = cscale(dv[w2], inv);
        }
        c2 sg = {0.f, 0.f};
        #pragma unroll
        for (int h = 0; h < 3; ++h)
            #pragma unroll
            for (int w2 = 0; w2 < 3; ++w2) {
                c2 mc = {m[2 * (h * 3 + w2)], m[2 * (h * 3 + w2) + 1]};
                sg = cadd(sg, cmul(mc, cjg(cmul(cprev[h], dv[w2]))));
            }
        float na     = sqrtf(ald(ctrl + CTRL_NA));
        float invsig = (na + EPSN) / (sqrtf(sg.x * sg.x + sg.y * sg.y) + EPSN);
        if (bid == 0 && tid == 0) ast32(ctrl + CTRL_SIG, invsig);
        return;
    }

    // ====================== CONV PATH (unnormalized weights) ==============
    __shared__ unsigned short lA[25344];   // [2ks][396 halo-pix][32ch]
    __shared__ unsigned short lB[32768];   // [2buf][2ks][256cout][32ci]

    const int cb   = blockIdx.x - NPB;                 // [0,512)
    const int bidc = ((cb & 7) << 6) + (cb >> 3);      // XCD-contiguous images
    const int b    = bidc >> 4;                        // image
    const int h0   = (bidc & 15) << 2;                 // output row base (4 rows)
    const int lane = tid & 63, wid = tid >> 6;
    const int l15  = lane & 15, q = lane >> 4;
    const int wm   = wid & 3;                          // wave's output row
    const int wn   = wid >> 2;                         // wave's cout64 group

    // A-halo stage source offsets: 3168 units of 16B cover [2ks][6r][66c][32ch]
    int asrc[4];
    #pragma unroll
    for (int j = 0; j < 4; ++j) {
        int u = (j < 3) ? ((j << 10) + tid) : (3072 + tid);
        if (u > 3167) u = 3167;                        // clamp (unissued lanes)
        int ks  = (u >= 1584) ? 1 : 0;
        int rem = u - ks * 1584;
        int pixA = rem >> 2, q4 = rem & 3;
        int rr = pixA / 66, cc2 = pixA - rr * 66;
        asrc[j] = ((b * 66 + h0 + rr) * 66 + cc2) * 256 + ks * 32 + q4 * 8;
    }
    // B stage source offsets: 2048 units cover [2ks][256cout][32ci]; ks = j
    int bsrc[2];
    #pragma unroll
    for (int j = 0; j < 2; ++j)
        bsrc[j] = ((tid >> 2) << 8) + (j << 5) + ((tid & 3) << 3);

    const int aro = ((wm * 66 + l15) << 5) + (q << 3); // frag base in lA
    const int bro = (((wn << 6) + l15) << 5) + (q << 3);

    f32x4 acc[4][4];
    #pragma unroll
    for (int ms = 0; ms < 4; ++ms)
        #pragma unroll
        for (int ns = 0; ns < 4; ++ns) acc[ms][ns] = {0.f, 0.f, 0.f, 0.f};

    #pragma unroll 1
    for (int cc = 0; cc < 4; ++cc) {
        const int cco = cc << 6;
        // stage A halo (50.7KB) + B tap0 into buf0
        #pragma unroll
        for (int j = 0; j < 3; ++j)
            gl_lds16(xb + asrc[j] + cco, lA + (((j << 10) + tid) << 3));
        if (tid < 96)
            gl_lds16(xb + asrc[3] + cco, lA + ((3072 + tid) << 3));
        #pragma unroll
        for (int j = 0; j < 2; ++j)
            gl_lds16(wt3u + bsrc[j] + cco, lB + (((j << 10) + tid) << 3));
        __syncthreads();

        int cur = 0;
        #pragma unroll 1
        for (int tap = 0; tap < 9; ++tap) {
            if (tap < 8) {                             // prefetch B(tap+1)
                #pragma unroll
                for (int j = 0; j < 2; ++j)
                    gl_lds16(wt3u + bsrc[j] + ((tap + 1) << 16) + cco,
                             lB + ((cur ^ 1) << 14) + (((j << 10) + tid) << 3));
            }
            const int kh = tap / 3, kw = tap - kh * 3;
            const int tko = (kh * 66 + kw) << 5;
            #pragma unroll
            for (int ks = 0; ks < 2; ++ks) {
                bf16x8 av[4], bv[4];
                #pragma unroll
                for (int ms = 0; ms < 4; ++ms)
                    av[ms] = *(const bf16x8*)(lA + ks * 12672 + tko + (ms << 9) + aro);
                #pragma unroll
                for (int ns = 0; ns < 4; ++ns)
                    bv[ns] = *(const bf16x8*)(lB + (cur << 14) + (ks << 13) + (ns << 9) + bro);
                #pragma unroll
                for (int ms = 0; ms < 4; ++ms)
                    #pragma unroll
                    for (int ns = 0; ns < 4; ++ns)
                        acc[ms][ns] = __builtin_amdgcn_mfma_f32_16x16x32_bf16(
                            av[ms], bv[ns], acc[ms][ns], 0, 0, 0);
            }
            __syncthreads();                           // prefetch landed + reads done
            cur ^= 1;
        }
    }

    // epilogue: UNSCALED y (scale+bias in k_scale)
    const int rowbase = (((b << 6) + h0 + wm) << 6);
    #pragma unroll
    for (int ms = 0; ms < 4; ++ms) {
        #pragma unroll
        for (int r2 = 0; r2 < 4; ++r2) {
            const int col = (ms << 4) + (q << 2) + r2;
            float* yr = y + (size_t)(rowbase + col) * 256 + (wn << 6);
            #pragma unroll
            for (int ns = 0; ns < 4; ++ns)
                yr[(ns << 4) + l15] = acc[ms][ns][r2];
        }
    }
}

// ---------------------------------------------------------------------------
// k_scale: y = y * invsig + bias.  grid 32768 x 256 (float4/thread).
// ---------------------------------------------------------------------------
__global__ __launch_bounds__(256) void k_scale(float* __restrict__ y,
                                               const float* __restrict__ bias,
                                               const float* __restrict__ ctrl) {
    const float inv = ctrl[CTRL_SIG];                  // post-kernel-boundary: coherent
    const int idx = blockIdx.x * 256 + threadIdx.x;
    float4 v = *(float4*)(y + (size_t)idx * 4);
    const float4 bv = *(const float4*)(bias + ((idx & 63) << 2));
    v.x = v.x * inv + bv.x;
    v.y = v.y * inv + bv.y;
    v.z = v.z * inv + bv.z;
    v.w = v.w * inv + bv.w;
    *(float4*)(y + (size_t)idx * 4) = v;
}

// ---------------------------------------------------------------------------
extern "C" void kernel_launch(void* const* d_in, const int* in_sizes, int n_in,
                              void* d_out, int out_size, void* d_ws, size_t ws_size,
                              hipStream_t stream) {
    const float* x    = (const float*)d_in[0];
    const float* w    = (const float*)d_in[1];
    const float* bias = (const float*)d_in[2];
    const float* u1   = (const float*)d_in[3];   // complex64 interleaved
    const float* u2   = (const float*)d_in[4];
    const float* u3   = (const float*)d_in[5];
    float* y = (float*)d_out;

    char* ws = (char*)d_ws;
    unsigned short* xb = (unsigned short*)(ws + XB_OFF);
    unsigned short* wt = (unsigned short*)(ws + WT_OFF);
    float*          ct = (float*)(ws + CTRL_OFF);

    k_xprep<<<35104, 256, 0, stream>>>(x, xb, ct, w, wt);
    k_fused<<<576, 1024, 0, stream>>>(xb, wt, w, u1, u2, u3, ct, y);
    k_scale<<<32768, 256, 0, stream>>>(y, bias, ct);
}